// Round 1
// baseline (823.855 us; speedup 1.0000x reference)
//
#include <hip/hip_runtime.h>
#include <hip/hip_bf16.h>
#include <float.h>

#define B_   8
#define C_   64
#define N_   4096
#define OUT_ 128
#define KNN  9
#define KEEP 12

// ---------------------------------------------------------------------------
// ws layout (bytes):
//   xT:    [B][N][C] float  @ 0          (8388608)
//   xmaxT: [B][N][C] float  @ 8388608    (8388608)
//   x2:    [B][N]    float  @ 16777216   (131072)
//   WT:    [2C][OUT] float  @ 16908288   (65536)
//   cand:  [B*N][12] int    @ 16973824   (1572864)
//   idx9:  [B*N][9]  int    @ 18546688   (1179648)   total ~19.7 MB
// ---------------------------------------------------------------------------

__global__ void k_wt(const float* __restrict__ W, float* __restrict__ WT) {
    int e = blockIdx.x * 256 + threadIdx.x;   // 0..16383
    int o = e >> 7, c = e & 127;              // W is [OUT][2C]
    WT[(size_t)c * OUT_ + o] = W[e];
}

__global__ void k_transpose(const float* __restrict__ x, float* __restrict__ xT,
                            float* __restrict__ x2) {
    __shared__ float t[C_][65];
    int b  = blockIdx.x >> 6;
    int n0 = (blockIdx.x & 63) * 64;
    int tid = threadIdx.x;
    for (int i = 0; i < 16; ++i) {
        int e = i * 256 + tid;
        int c = e >> 6, nn = e & 63;
        t[c][nn] = x[((size_t)b * C_ + c) * N_ + n0 + nn];
    }
    __syncthreads();
    for (int i = 0; i < 16; ++i) {
        int e = i * 256 + tid;
        int nn = e >> 6, c = e & 63;
        xT[((size_t)b * N_ + n0 + nn) * C_ + c] = t[c][nn];
    }
    if (tid < 64) {
        float s = 0.f;
        for (int c = 0; c < C_; ++c) { float v = t[c][tid]; s += v * v; }
        x2[(size_t)b * N_ + n0 + tid] = s;
    }
}

// top-12 (by key = 2*<xi,xm> - |xm|^2, == neg_dist + const per row) per row.
// block: 256 threads = 4 waves; lanes = 64 rows; wave w scans m in [w*1024,(w+1)*1024)
__global__ __launch_bounds__(256, 2) void k_topk(const float* __restrict__ xT,
                                                 const float* __restrict__ x2,
                                                 int* __restrict__ cand) {
    __shared__ __align__(16) float tile[4][64 * 64];  // per-wave staging
    __shared__ float x2t[4][64];
    int b    = blockIdx.x >> 6;
    int rt   = blockIdx.x & 63;
    int wave = threadIdx.x >> 6;
    int lane = threadIdx.x & 63;
    int n    = rt * 64 + lane;

    float4 xi[16];
    const float4* xrow = (const float4*)(xT + ((size_t)b * N_ + n) * C_);
#pragma unroll
    for (int j = 0; j < 16; ++j) xi[j] = xrow[j];

    float s[KEEP]; int si[KEEP];
#pragma unroll
    for (int j = 0; j < KEEP; ++j) { s[j] = -FLT_MAX; si[j] = 0; }

    float* my = tile[wave];
    int mbase = wave * 1024;

    for (int tb = 0; tb < 16; ++tb) {
        int m0 = mbase + tb * 64;
        __syncthreads();
        float4* dst = (float4*)my;
        const float4* src = (const float4*)(xT + ((size_t)b * N_ + m0) * C_);
#pragma unroll
        for (int i = 0; i < 16; ++i) dst[i * 64 + lane] = src[i * 64 + lane];
        x2t[wave][lane] = x2[(size_t)b * N_ + m0 + lane];
        __syncthreads();

        for (int t = 0; t < 64; ++t) {
            const float4* col = (const float4*)(my + t * 64);
            float4 d = {0.f, 0.f, 0.f, 0.f};
#pragma unroll
            for (int c4 = 0; c4 < 16; ++c4) {
                float4 v = col[c4];          // broadcast ds_read_b128
                d.x += xi[c4].x * v.x;
                d.y += xi[c4].y * v.y;
                d.z += xi[c4].z * v.z;
                d.w += xi[c4].w * v.w;
            }
            float key = 2.f * ((d.x + d.y) + (d.z + d.w)) - x2t[wave][t];
            if (key > s[0]) {                // strict: ties keep lower index
                s[0] = key; si[0] = m0 + t;
#pragma unroll
                for (int j = 0; j < KEEP - 1; ++j) {
                    bool sw = s[j] > s[j + 1];
                    float tk = s[j]; int ti = si[j];
                    s[j]      = sw ? s[j + 1] : s[j];
                    si[j]     = sw ? si[j + 1] : si[j];
                    s[j + 1]  = sw ? tk : s[j + 1];
                    si[j + 1] = sw ? ti : si[j + 1];
                }
            }
        }
    }
    __syncthreads();
    // merge 4 waves x 12 -> top-12 per row (reuse tile area)
    float* mk = tile[0];
    int*   mi = (int*)tile[1];
#pragma unroll
    for (int j = 0; j < KEEP; ++j) {
        mk[(lane * 4 + wave) * KEEP + j] = s[j];
        mi[(lane * 4 + wave) * KEEP + j] = si[j];
    }
    __syncthreads();
    if (threadIdx.x < 64) {
        int row  = threadIdx.x;
        int base = row * 4 * KEEP;
        size_t gout = ((size_t)b * N_ + rt * 64 + row) * KEEP;
        for (int r = 0; r < KEEP; ++r) {
            float bk = -FLT_MAX; int bi = 0x7fffffff; int bq = 0;
            for (int q = 0; q < 4 * KEEP; ++q) {
                float kq = mk[base + q]; int iq = mi[base + q];
                if (kq > bk || (kq == bk && iq < bi)) { bk = kq; bi = iq; bq = q; }
            }
            mk[base + bq] = -FLT_MAX;
            cand[gout + r] = bi;
        }
    }
}

// fp64 exact re-rank of the 12 candidates -> true top-9 (matches reference
// selection regardless of fp32 summation-order differences at boundaries)
__global__ void k_refine(const float* __restrict__ xT, const int* __restrict__ cand,
                         int* __restrict__ idx9) {
    int row = blockIdx.x * 256 + threadIdx.x;   // 0..32767
    int b = row >> 12;
    int n = row & (N_ - 1);
    const float* xi = xT + ((size_t)b * N_ + n) * C_;
    double key[KEEP]; int id[KEEP];
    for (int j = 0; j < KEEP; ++j) {
        int m = cand[(size_t)row * KEEP + j];
        const float* xm = xT + ((size_t)b * N_ + m) * C_;
        double dot = 0.0, s2 = 0.0;
        for (int c = 0; c < C_; ++c) {
            double v = (double)xm[c];
            dot += (double)xi[c] * v;
            s2  += v * v;
        }
        key[j] = 2.0 * dot - s2;
        id[j]  = m;
    }
    for (int r = 0; r < KNN; ++r) {
        int bq = 0; double bk = -1e300; int bi = 0x7fffffff;
        for (int q = 0; q < KEEP; ++q) {
            if (key[q] > bk || (key[q] == bk && id[q] < bi)) {
                bk = key[q]; bi = id[q]; bq = q;
            }
        }
        key[bq] = -1e300;
        idx9[(size_t)row * KNN + r] = bi;
    }
}

// xmaxT[b][n][c] = max_k xT[b][idx_k][c] - xT[b][n][c]
__global__ void k_xmax(const float* __restrict__ xT, const int* __restrict__ idx9,
                       float* __restrict__ xmaxT) {
    int wave = threadIdx.x >> 6, lane = threadIdx.x & 63;
    int row = blockIdx.x * 4 + wave;            // 0..32767
    int b = row >> 12;
    int n = row & (N_ - 1);
    const int* id = idx9 + (size_t)row * KNN;
    float m = -FLT_MAX;
#pragma unroll
    for (int k = 0; k < KNN; ++k) {
        int j = id[k];
        m = fmaxf(m, xT[((size_t)b * N_ + j) * C_ + lane]);
    }
    float xic = xT[((size_t)b * N_ + n) * C_ + lane];
    xmaxT[(size_t)row * C_ + lane] = m - xic;
}

// out[b][o][n] = relu( sum_c W[o][c]*x[b][c][n] + W[o][C+c]*xmax[b][c][n] + bias[o] )
__global__ void k_gemm(const float* __restrict__ xT, const float* __restrict__ xmaxT,
                       const float* __restrict__ WT, const float* __restrict__ bias,
                       float* __restrict__ out) {
    __shared__ float h[64][129];
    int b  = blockIdx.x >> 6;
    int n0 = (blockIdx.x & 63) * 64;
    int tid = threadIdx.x;
    for (int i = 0; i < 16; ++i) {
        int e = i * 256 + tid;
        int nn = e >> 6, c = e & 63;
        size_t g = ((size_t)b * N_ + n0 + nn) * C_ + c;
        h[nn][c]      = xT[g];
        h[nn][64 + c] = xmaxT[g];
    }
    __syncthreads();
    int wave = tid >> 6, lane = tid & 63;
    int o0 = wave * 32;
    float acc[32];
#pragma unroll
    for (int j = 0; j < 32; ++j) acc[j] = 0.f;
    for (int c = 0; c < 2 * C_; ++c) {
        float hv = h[lane][c];
        const float4* wrow = (const float4*)(WT + (size_t)c * OUT_ + o0);
#pragma unroll
        for (int j4 = 0; j4 < 8; ++j4) {
            float4 w = wrow[j4];
            acc[j4 * 4 + 0] += w.x * hv;
            acc[j4 * 4 + 1] += w.y * hv;
            acc[j4 * 4 + 2] += w.z * hv;
            acc[j4 * 4 + 3] += w.w * hv;
        }
    }
#pragma unroll
    for (int j = 0; j < 32; ++j) {
        float v = acc[j] + bias[o0 + j];
        v = fmaxf(v, 0.f);
        out[((size_t)b * OUT_ + o0 + j) * N_ + n0 + lane] = v;
    }
}

extern "C" void kernel_launch(void* const* d_in, const int* in_sizes, int n_in,
                              void* d_out, int out_size, void* d_ws, size_t ws_size,
                              hipStream_t stream) {
    const float* x    = (const float*)d_in[0];
    const float* W    = (const float*)d_in[1];
    const float* bias = (const float*)d_in[2];
    float* out = (float*)d_out;
    char* ws = (char*)d_ws;

    float* xT    = (float*)(ws);
    float* xmaxT = (float*)(ws + 8388608);
    float* x2    = (float*)(ws + 16777216);
    float* WT    = (float*)(ws + 16908288);
    int*   cand  = (int*)(ws + 16973824);
    int*   idx9  = (int*)(ws + 18546688);

    k_wt<<<dim3(64), dim3(256), 0, stream>>>(W, WT);
    k_transpose<<<dim3(512), dim3(256), 0, stream>>>(x, xT, x2);
    k_topk<<<dim3(512), dim3(256), 0, stream>>>(xT, x2, cand);
    k_refine<<<dim3(128), dim3(256), 0, stream>>>(xT, cand, idx9);
    k_xmax<<<dim3(8192), dim3(256), 0, stream>>>(xT, idx9, xmaxT);
    k_gemm<<<dim3(512), dim3(256), 0, stream>>>(xT, xmaxT, WT, bias, out);
}

// Round 2
// 617.046 us; speedup vs baseline: 1.3352x; 1.3352x over previous
//
#include <hip/hip_runtime.h>
#include <float.h>

#define B_   8
#define C_   64
#define N_   4096
#define OUT_ 128
#define KNN  9
#define KEEP 12

typedef __attribute__((ext_vector_type(8))) short short8;
typedef __attribute__((ext_vector_type(4))) float f32x4;

__device__ inline unsigned short f2bf(float f) {
    unsigned u = __float_as_uint(f);
    unsigned r = (u + 0x7fffu + ((u >> 16) & 1u)) >> 16;
    return (unsigned short)r;
}
__device__ inline float bf2f(unsigned short s) {
    return __uint_as_float(((unsigned)s) << 16);
}

// ---------------------------------------------------------------------------
// ws layout (bytes):
//   xT:    [B][N][C] float     @ 0          (8388608)
//   xfrag: hi/lo bf16 chunks   @ 8388608    (8388608)  } aliased: xfrag dead
//   xmaxT: [B][N][C] float     @ 8388608    (8388608)  } before k_xmax writes
//   x2:    [B][N]    float     @ 16777216   (131072)
//   WT:    [2C][OUT] float     @ 16908288   (65536)
//   cand:  [B*N][12] int       @ 16973824   (1572864)
//   idx9:  [B*N][9]  int       @ 18546688   (1179648)   total ~19.7 MB
//
// xfrag: per (b, tile t=m/16, khalf h, part p∈{hi,lo}) a 1024B chunk;
// lane L holds 8 bf16 = x[b][m=t*16+(L&15)][k=h*32+(L>>4)*8 .. +7] at L*16B.
// This is exactly the mfma_f32_16x16x32_bf16 A/B fragment load order.
// ---------------------------------------------------------------------------

__global__ void k_wt(const float* __restrict__ W, float* __restrict__ WT) {
    int e = blockIdx.x * 256 + threadIdx.x;
    int o = e >> 7, c = e & 127;
    WT[(size_t)c * OUT_ + o] = W[e];
}

__global__ void k_transpose(const float* __restrict__ x, float* __restrict__ xT,
                            float* __restrict__ x2) {
    __shared__ float t[C_][65];
    int b  = blockIdx.x >> 6;
    int n0 = (blockIdx.x & 63) * 64;
    int tid = threadIdx.x;
    for (int i = 0; i < 16; ++i) {
        int e = i * 256 + tid;
        int c = e >> 6, nn = e & 63;
        t[c][nn] = x[((size_t)b * C_ + c) * N_ + n0 + nn];
    }
    __syncthreads();
    for (int i = 0; i < 16; ++i) {
        int e = i * 256 + tid;
        int nn = e >> 6, c = e & 63;
        xT[((size_t)b * N_ + n0 + nn) * C_ + c] = t[c][nn];
    }
    if (tid < 64) {
        float s = 0.f;
        for (int c = 0; c < C_; ++c) { float v = t[c][tid]; s += v * v; }
        x2[(size_t)b * N_ + n0 + tid] = s;
    }
}

// build bf16 hi/lo fragment chunks from xT
__global__ void k_prep(const float* __restrict__ xT, unsigned short* __restrict__ xfrag) {
    int tid = threadIdx.x;
    int t = blockIdx.x * 2 + (tid >> 7);        // global m-tile 0..2047
    int h = (tid >> 6) & 1;
    int L = tid & 63;
    int b = t >> 8, tb = t & 255;
    int m = tb * 16 + (L & 15);
    int ks = h * 32 + ((L >> 4) * 8);
    const float* src = xT + ((size_t)b * N_ + m) * C_ + ks;
    float4 v0 = *(const float4*)(src);
    float4 v1 = *(const float4*)(src + 4);
    float vs[8] = {v0.x, v0.y, v0.z, v0.w, v1.x, v1.y, v1.z, v1.w};
    short8 hi, lo;
#pragma unroll
    for (int j = 0; j < 8; ++j) {
        unsigned short hb = f2bf(vs[j]);
        float hf = bf2f(hb);
        unsigned short lb = f2bf(vs[j] - hf);
        hi[j] = (short)hb; lo[j] = (short)lb;
    }
    size_t cb = ((size_t)t * 4 + h * 2) * 512;   // ushort units (chunk=512 ushort)
    *(short8*)(xfrag + cb + L * 8)       = hi;
    *(short8*)(xfrag + cb + 512 + L * 8) = lo;
}

#define INSERT(S, SI, key, idx)                                         \
    if ((key) > S[0]) {                                                 \
        S[0] = (key); SI[0] = (idx);                                    \
        _Pragma("unroll")                                               \
        for (int jj = 0; jj < KEEP - 1; ++jj) {                         \
            bool sw = S[jj] > S[jj + 1];                                \
            float tk = S[jj]; int ti = SI[jj];                          \
            S[jj]     = sw ? S[jj + 1] : S[jj];                         \
            SI[jj]    = sw ? SI[jj + 1] : SI[jj];                       \
            S[jj + 1] = sw ? tk : S[jj + 1];                            \
            SI[jj + 1]= sw ? ti : SI[jj + 1];                           \
        }                                                               \
    }

// MFMA scan: block = (batch b = blockIdx&7, n-group ng = blockIdx>>3, 32 n's).
// wave w scans m in [w*1024,(w+1)*1024). Lane owns n = ng*32 + q*16 + (lane&15),
// sees m rows (lane>>4)*4+j of each 16-m tile -> per-lane top-12, 16-way merge.
__global__ __launch_bounds__(256, 2) void k_topk_mf(const unsigned short* __restrict__ xfrag,
                                                    const float* __restrict__ x2,
                                                    int* __restrict__ cand) {
    __shared__ float mk[2 * 16 * 16 * 13];
    __shared__ int   mi[2 * 16 * 16 * 13];
    int b    = blockIdx.x & 7;
    int ng   = blockIdx.x >> 3;
    int wave = threadIdx.x >> 6, lane = threadIdx.x & 63;

    const short8* fr = (const short8*)xfrag;     // 16B units; chunk = 64 short8

    short8 Bh[2][2], Bl[2][2];
#pragma unroll
    for (int q = 0; q < 2; ++q)
#pragma unroll
        for (int h = 0; h < 2; ++h) {
            int ch = ((b * 256 + ng * 2 + q) * 4 + h * 2);
            Bh[q][h] = fr[(size_t)ch * 64 + lane];
            Bl[q][h] = fr[(size_t)(ch + 1) * 64 + lane];
        }

    float s0[KEEP], s1[KEEP]; int i0[KEEP], i1[KEEP];
#pragma unroll
    for (int j = 0; j < KEEP; ++j) { s0[j] = -FLT_MAX; s1[j] = -FLT_MAX; i0[j] = 0; i1[j] = 0; }

    int mt0 = wave * 64;
    size_t cb = (size_t)(b * 256 + mt0) * 4;
    short8 Ah0 = fr[cb * 64 + lane],       Al0 = fr[(cb + 1) * 64 + lane];
    short8 Ah1 = fr[(cb + 2) * 64 + lane], Al1 = fr[(cb + 3) * 64 + lane];
    f32x4 x2v = *(const f32x4*)(x2 + b * N_ + mt0 * 16 + (lane >> 4) * 4);

    for (int i = 0; i < 64; ++i) {
        int inext = (i + 1 < 64) ? i + 1 : i;
        size_t cn = (size_t)(b * 256 + mt0 + inext) * 4;
        short8 nAh0 = fr[cn * 64 + lane],       nAl0 = fr[(cn + 1) * 64 + lane];
        short8 nAh1 = fr[(cn + 2) * 64 + lane], nAl1 = fr[(cn + 3) * 64 + lane];
        f32x4 nx2 = *(const f32x4*)(x2 + b * N_ + (mt0 + inext) * 16 + (lane >> 4) * 4);

        int mbase = (mt0 + i) * 16 + (lane >> 4) * 4;

        {   // n-tile 0
            f32x4 acc = {0.f, 0.f, 0.f, 0.f};
            acc = __builtin_amdgcn_mfma_f32_16x16x32_bf16(Ah0, Bh[0][0], acc, 0, 0, 0);
            acc = __builtin_amdgcn_mfma_f32_16x16x32_bf16(Ah1, Bh[0][1], acc, 0, 0, 0);
            acc = __builtin_amdgcn_mfma_f32_16x16x32_bf16(Al0, Bh[0][0], acc, 0, 0, 0);
            acc = __builtin_amdgcn_mfma_f32_16x16x32_bf16(Al1, Bh[0][1], acc, 0, 0, 0);
            acc = __builtin_amdgcn_mfma_f32_16x16x32_bf16(Ah0, Bl[0][0], acc, 0, 0, 0);
            acc = __builtin_amdgcn_mfma_f32_16x16x32_bf16(Ah1, Bl[0][1], acc, 0, 0, 0);
            float k0 = 2.f * acc[0] - x2v[0], k1 = 2.f * acc[1] - x2v[1];
            float k2 = 2.f * acc[2] - x2v[2], k3 = 2.f * acc[3] - x2v[3];
            float kmax = fmaxf(fmaxf(k0, k1), fmaxf(k2, k3));
            if (kmax > s0[0]) {
                INSERT(s0, i0, k0, mbase + 0); INSERT(s0, i0, k1, mbase + 1);
                INSERT(s0, i0, k2, mbase + 2); INSERT(s0, i0, k3, mbase + 3);
            }
        }
        {   // n-tile 1
            f32x4 acc = {0.f, 0.f, 0.f, 0.f};
            acc = __builtin_amdgcn_mfma_f32_16x16x32_bf16(Ah0, Bh[1][0], acc, 0, 0, 0);
            acc = __builtin_amdgcn_mfma_f32_16x16x32_bf16(Ah1, Bh[1][1], acc, 0, 0, 0);
            acc = __builtin_amdgcn_mfma_f32_16x16x32_bf16(Al0, Bh[1][0], acc, 0, 0, 0);
            acc = __builtin_amdgcn_mfma_f32_16x16x32_bf16(Al1, Bh[1][1], acc, 0, 0, 0);
            acc = __builtin_amdgcn_mfma_f32_16x16x32_bf16(Ah0, Bl[1][0], acc, 0, 0, 0);
            acc = __builtin_amdgcn_mfma_f32_16x16x32_bf16(Ah1, Bl[1][1], acc, 0, 0, 0);
            float k0 = 2.f * acc[0] - x2v[0], k1 = 2.f * acc[1] - x2v[1];
            float k2 = 2.f * acc[2] - x2v[2], k3 = 2.f * acc[3] - x2v[3];
            float kmax = fmaxf(fmaxf(k0, k1), fmaxf(k2, k3));
            if (kmax > s1[0]) {
                INSERT(s1, i1, k0, mbase + 0); INSERT(s1, i1, k1, mbase + 1);
                INSERT(s1, i1, k2, mbase + 2); INSERT(s1, i1, k3, mbase + 3);
            }
        }
        Ah0 = nAh0; Al0 = nAl0; Ah1 = nAh1; Al1 = nAl1; x2v = nx2;
    }

    __syncthreads();
    int slot = wave * 4 + (lane >> 4);
    int v = lane & 15;
    int base0 = ((0 * 16 + v) * 16 + slot) * 13;
    int base1 = ((1 * 16 + v) * 16 + slot) * 13;
#pragma unroll
    for (int j = 0; j < KEEP; ++j) {
        mk[base0 + j] = s0[j]; mi[base0 + j] = i0[j];
        mk[base1 + j] = s1[j]; mi[base1 + j] = i1[j];
    }
    __syncthreads();
    if (threadIdx.x < 32) {
        int q = threadIdx.x >> 4, vv = threadIdx.x & 15;
        int hh[16];
#pragma unroll
        for (int l = 0; l < 16; ++l) hh[l] = KEEP - 1;
        int n = ng * 32 + q * 16 + vv;
        size_t out = ((size_t)b * N_ + n) * KEEP;
        for (int r = 0; r < KEEP; ++r) {
            float bk = -FLT_MAX; int bi = 0x7fffffff; int bl = 0;
#pragma unroll
            for (int l = 0; l < 16; ++l) {
                int idxl = ((q * 16 + vv) * 16 + l) * 13 + hh[l];
                float kq = (hh[l] >= 0) ? mk[idxl] : -FLT_MAX;
                int   iq = (hh[l] >= 0) ? mi[idxl] : 0x7fffffff;
                bool better = (kq > bk) || (kq == bk && iq < bi);
                bk = better ? kq : bk; bi = better ? iq : bi; bl = better ? l : bl;
            }
#pragma unroll
            for (int l = 0; l < 16; ++l) hh[l] -= (l == bl) ? 1 : 0;
            cand[out + r] = bi;
        }
    }
}

// fp64 exact re-rank of the 12 candidates -> true top-9
__global__ void k_refine(const float* __restrict__ xT, const int* __restrict__ cand,
                         int* __restrict__ idx9) {
    int row = blockIdx.x * 256 + threadIdx.x;
    int b = row >> 12;
    int n = row & (N_ - 1);
    const float* xi = xT + ((size_t)b * N_ + n) * C_;
    double key[KEEP]; int id[KEEP];
    for (int j = 0; j < KEEP; ++j) {
        int m = cand[(size_t)row * KEEP + j];
        const float* xm = xT + ((size_t)b * N_ + m) * C_;
        double dot = 0.0, s2 = 0.0;
        for (int c = 0; c < C_; ++c) {
            double v = (double)xm[c];
            dot += (double)xi[c] * v;
            s2  += v * v;
        }
        key[j] = 2.0 * dot - s2;
        id[j]  = m;
    }
    for (int r = 0; r < KNN; ++r) {
        int bq = 0; double bk = -1e300; int bi = 0x7fffffff;
        for (int q = 0; q < KEEP; ++q) {
            if (key[q] > bk || (key[q] == bk && id[q] < bi)) {
                bk = key[q]; bi = id[q]; bq = q;
            }
        }
        key[bq] = -1e300;
        idx9[(size_t)row * KNN + r] = bi;
    }
}

__global__ void k_xmax(const float* __restrict__ xT, const int* __restrict__ idx9,
                       float* __restrict__ xmaxT) {
    int wave = threadIdx.x >> 6, lane = threadIdx.x & 63;
    int row = blockIdx.x * 4 + wave;
    int b = row >> 12;
    int n = row & (N_ - 1);
    const int* id = idx9 + (size_t)row * KNN;
    float m = -FLT_MAX;
#pragma unroll
    for (int k = 0; k < KNN; ++k) {
        int j = id[k];
        m = fmaxf(m, xT[((size_t)b * N_ + j) * C_ + lane]);
    }
    float xic = xT[((size_t)b * N_ + n) * C_ + lane];
    xmaxT[(size_t)row * C_ + lane] = m - xic;
}

__global__ void k_gemm(const float* __restrict__ xT, const float* __restrict__ xmaxT,
                       const float* __restrict__ WT, const float* __restrict__ bias,
                       float* __restrict__ out) {
    __shared__ float h[64][129];
    int b  = blockIdx.x >> 6;
    int n0 = (blockIdx.x & 63) * 64;
    int tid = threadIdx.x;
    for (int i = 0; i < 16; ++i) {
        int e = i * 256 + tid;
        int nn = e >> 6, c = e & 63;
        size_t g = ((size_t)b * N_ + n0 + nn) * C_ + c;
        h[nn][c]      = xT[g];
        h[nn][64 + c] = xmaxT[g];
    }
    __syncthreads();
    int wave = tid >> 6, lane = tid & 63;
    int o0 = wave * 32;
    float acc[32];
#pragma unroll
    for (int j = 0; j < 32; ++j) acc[j] = 0.f;
    for (int c = 0; c < 2 * C_; ++c) {
        float hv = h[lane][c];
        const float4* wrow = (const float4*)(WT + (size_t)c * OUT_ + o0);
#pragma unroll
        for (int j4 = 0; j4 < 8; ++j4) {
            float4 w = wrow[j4];
            acc[j4 * 4 + 0] += w.x * hv;
            acc[j4 * 4 + 1] += w.y * hv;
            acc[j4 * 4 + 2] += w.z * hv;
            acc[j4 * 4 + 3] += w.w * hv;
        }
    }
#pragma unroll
    for (int j = 0; j < 32; ++j) {
        float v = acc[j] + bias[o0 + j];
        v = fmaxf(v, 0.f);
        out[((size_t)b * OUT_ + o0 + j) * N_ + n0 + lane] = v;
    }
}

extern "C" void kernel_launch(void* const* d_in, const int* in_sizes, int n_in,
                              void* d_out, int out_size, void* d_ws, size_t ws_size,
                              hipStream_t stream) {
    const float* x    = (const float*)d_in[0];
    const float* W    = (const float*)d_in[1];
    const float* bias = (const float*)d_in[2];
    float* out = (float*)d_out;
    char* ws = (char*)d_ws;

    float*          xT    = (float*)(ws);
    unsigned short* xfrag = (unsigned short*)(ws + 8388608);
    float*          xmaxT = (float*)(ws + 8388608);       // aliases xfrag (dead by then)
    float*          x2    = (float*)(ws + 16777216);
    float*          WT    = (float*)(ws + 16908288);
    int*            cand  = (int*)(ws + 16973824);
    int*            idx9  = (int*)(ws + 18546688);

    k_wt       <<<dim3(64),   dim3(256), 0, stream>>>(W, WT);
    k_transpose<<<dim3(512),  dim3(256), 0, stream>>>(x, xT, x2);
    k_prep     <<<dim3(1024), dim3(256), 0, stream>>>(xT, xfrag);
    k_topk_mf  <<<dim3(1024), dim3(256), 0, stream>>>(xfrag, x2, cand);
    k_refine   <<<dim3(128),  dim3(256), 0, stream>>>(xT, cand, idx9);
    k_xmax     <<<dim3(8192), dim3(256), 0, stream>>>(xT, idx9, xmaxT);
    k_gemm     <<<dim3(512),  dim3(256), 0, stream>>>(xT, xmaxT, WT, bias, out);
}

// Round 3
// 558.960 us; speedup vs baseline: 1.4739x; 1.1039x over previous
//
#include <hip/hip_runtime.h>
#include <float.h>

#define B_   8
#define C_   64
#define N_   4096
#define OUT_ 128
#define KNN  9
#define CAP  64          // candidate buffer capacity per row (refine handles <=64)
#define TAU_A 2.3f       // threshold: tau = TAU_A*sigma_n - 64

typedef __attribute__((ext_vector_type(8))) short short8;
typedef __attribute__((ext_vector_type(4))) float f32x4;

__device__ inline unsigned short f2bf(float f) {
    unsigned u = __float_as_uint(f);
    unsigned r = (u + 0x7fffu + ((u >> 16) & 1u)) >> 16;
    return (unsigned short)r;
}
__device__ inline float bf2f(unsigned short s) {
    return __uint_as_float(((unsigned)s) << 16);
}

// ---------------------------------------------------------------------------
// ws layout (bytes):
//   xT:    [B][N][C] float     @ 0          (8388608)
//   xfrag: hi/lo bf16 chunks   @ 8388608    (8388608)  } aliased: xfrag dead
//   xmaxT: [B][N][C] float     @ 8388608    (8388608)  } before k_xmax writes
//   x2:    [B][N]    float     @ 16777216   (131072)
//   WT:    [2C][OUT] float     @ 16908288   (65536)
//   cand:  [B*N][64] ushort    @ 16973824   (4194304)
//   cnt:   [B*N]     int       @ 21168128   (131072)
//   idx9:  [B*N][9]  int       @ 21299200   (1179648)   total ~22.5 MB
// ---------------------------------------------------------------------------

__global__ void k_wt(const float* __restrict__ W, float* __restrict__ WT) {
    int e = blockIdx.x * 256 + threadIdx.x;
    int o = e >> 7, c = e & 127;
    WT[(size_t)c * OUT_ + o] = W[e];
}

__global__ void k_transpose(const float* __restrict__ x, float* __restrict__ xT,
                            float* __restrict__ x2) {
    __shared__ float t[C_][65];
    int b  = blockIdx.x >> 6;
    int n0 = (blockIdx.x & 63) * 64;
    int tid = threadIdx.x;
    for (int i = 0; i < 16; ++i) {
        int e = i * 256 + tid;
        int c = e >> 6, nn = e & 63;
        t[c][nn] = x[((size_t)b * C_ + c) * N_ + n0 + nn];
    }
    __syncthreads();
    for (int i = 0; i < 16; ++i) {
        int e = i * 256 + tid;
        int nn = e >> 6, c = e & 63;
        xT[((size_t)b * N_ + n0 + nn) * C_ + c] = t[c][nn];
    }
    if (tid < 64) {
        float s = 0.f;
        for (int c = 0; c < C_; ++c) { float v = t[c][tid]; s += v * v; }
        x2[(size_t)b * N_ + n0 + tid] = s;
    }
}

// build bf16 hi/lo fragment chunks from xT (mfma_f32_16x16x32_bf16 load order)
__global__ void k_prep(const float* __restrict__ xT, unsigned short* __restrict__ xfrag) {
    int tid = threadIdx.x;
    int t = blockIdx.x * 2 + (tid >> 7);        // global m-tile 0..2047
    int h = (tid >> 6) & 1;
    int L = tid & 63;
    int b = t >> 8, tb = t & 255;
    int m = tb * 16 + (L & 15);
    int ks = h * 32 + ((L >> 4) * 8);
    const float* src = xT + ((size_t)b * N_ + m) * C_ + ks;
    float4 v0 = *(const float4*)(src);
    float4 v1 = *(const float4*)(src + 4);
    float vs[8] = {v0.x, v0.y, v0.z, v0.w, v1.x, v1.y, v1.z, v1.w};
    short8 hi, lo;
#pragma unroll
    for (int j = 0; j < 8; ++j) {
        unsigned short hb = f2bf(vs[j]);
        float hf = bf2f(hb);
        unsigned short lb = f2bf(vs[j] - hf);
        hi[j] = (short)hb; lo[j] = (short)lb;
    }
    size_t cb = ((size_t)t * 4 + h * 2) * 512;   // ushort units (chunk=512 ushort)
    *(short8*)(xfrag + cb + L * 8)       = hi;
    *(short8*)(xfrag + cb + 512 + L * 8) = lo;
}

#define APPEND(KEY, TAU, LN, MIDX)                                      \
    if ((KEY) > (TAU)) {                                                \
        int sl = atomicAdd(&cnt_s[LN], 1);                              \
        if (sl < CAP) buf_s[LN][sl] = (unsigned short)(MIDX);           \
    }

// MFMA scan + threshold compaction. block = (b = blockIdx&7, ng = blockIdx>>3).
// 32 n's per block; wave w scans m in [w*1024,(w+1)*1024).
__global__ __launch_bounds__(256, 2) void k_topk_mf(const unsigned short* __restrict__ xfrag,
                                                    const float* __restrict__ x2,
                                                    unsigned short* __restrict__ candg,
                                                    int* __restrict__ cntg) {
    __shared__ int cnt_s[32];
    __shared__ unsigned short buf_s[32][CAP];
    int b    = blockIdx.x & 7;
    int ng   = blockIdx.x >> 3;
    int wave = threadIdx.x >> 6, lane = threadIdx.x & 63;
    if (threadIdx.x < 32) cnt_s[threadIdx.x] = 0;

    const short8* fr = (const short8*)xfrag;     // 16B units; chunk = 64 short8

    short8 Bh[2][2], Bl[2][2];
#pragma unroll
    for (int q = 0; q < 2; ++q)
#pragma unroll
        for (int h = 0; h < 2; ++h) {
            int ch = ((b * 256 + ng * 2 + q) * 4 + h * 2);
            Bh[q][h] = fr[(size_t)ch * 64 + lane];
            Bl[q][h] = fr[(size_t)(ch + 1) * 64 + lane];
        }

    int ln0 = lane & 15, ln1 = 16 + ln0;
    float x2n0 = x2[b * N_ + ng * 32 + ln0];
    float x2n1 = x2[b * N_ + ng * 32 + 16 + ln0];
    float tau0 = TAU_A * sqrtf(fmaf(4.f, x2n0, 128.f)) - 64.f;
    float tau1 = TAU_A * sqrtf(fmaf(4.f, x2n1, 128.f)) - 64.f;

    int mt0 = wave * 64;
    size_t cb = (size_t)(b * 256 + mt0) * 4;
    short8 Ah0 = fr[cb * 64 + lane],       Al0 = fr[(cb + 1) * 64 + lane];
    short8 Ah1 = fr[(cb + 2) * 64 + lane], Al1 = fr[(cb + 3) * 64 + lane];
    f32x4 x2v = *(const f32x4*)(x2 + b * N_ + mt0 * 16 + (lane >> 4) * 4);

    __syncthreads();   // cnt_s zeroed

    for (int i = 0; i < 64; ++i) {
        int inext = (i + 1 < 64) ? i + 1 : i;
        size_t cn = (size_t)(b * 256 + mt0 + inext) * 4;
        short8 nAh0 = fr[cn * 64 + lane],       nAl0 = fr[(cn + 1) * 64 + lane];
        short8 nAh1 = fr[(cn + 2) * 64 + lane], nAl1 = fr[(cn + 3) * 64 + lane];
        f32x4 nx2 = *(const f32x4*)(x2 + b * N_ + (mt0 + inext) * 16 + (lane >> 4) * 4);

        int mbase = (mt0 + i) * 16 + (lane >> 4) * 4;

        {   // n-tile 0
            f32x4 acc = {0.f, 0.f, 0.f, 0.f};
            acc = __builtin_amdgcn_mfma_f32_16x16x32_bf16(Ah0, Bh[0][0], acc, 0, 0, 0);
            acc = __builtin_amdgcn_mfma_f32_16x16x32_bf16(Ah1, Bh[0][1], acc, 0, 0, 0);
            acc = __builtin_amdgcn_mfma_f32_16x16x32_bf16(Al0, Bh[0][0], acc, 0, 0, 0);
            acc = __builtin_amdgcn_mfma_f32_16x16x32_bf16(Al1, Bh[0][1], acc, 0, 0, 0);
            acc = __builtin_amdgcn_mfma_f32_16x16x32_bf16(Ah0, Bl[0][0], acc, 0, 0, 0);
            acc = __builtin_amdgcn_mfma_f32_16x16x32_bf16(Ah1, Bl[0][1], acc, 0, 0, 0);
            float k0 = fmaf(2.f, acc[0], -x2v[0]);
            float k1 = fmaf(2.f, acc[1], -x2v[1]);
            float k2 = fmaf(2.f, acc[2], -x2v[2]);
            float k3 = fmaf(2.f, acc[3], -x2v[3]);
            APPEND(k0, tau0, ln0, mbase + 0)
            APPEND(k1, tau0, ln0, mbase + 1)
            APPEND(k2, tau0, ln0, mbase + 2)
            APPEND(k3, tau0, ln0, mbase + 3)
        }
        {   // n-tile 1
            f32x4 acc = {0.f, 0.f, 0.f, 0.f};
            acc = __builtin_amdgcn_mfma_f32_16x16x32_bf16(Ah0, Bh[1][0], acc, 0, 0, 0);
            acc = __builtin_amdgcn_mfma_f32_16x16x32_bf16(Ah1, Bh[1][1], acc, 0, 0, 0);
            acc = __builtin_amdgcn_mfma_f32_16x16x32_bf16(Al0, Bh[1][0], acc, 0, 0, 0);
            acc = __builtin_amdgcn_mfma_f32_16x16x32_bf16(Al1, Bh[1][1], acc, 0, 0, 0);
            acc = __builtin_amdgcn_mfma_f32_16x16x32_bf16(Ah0, Bl[1][0], acc, 0, 0, 0);
            acc = __builtin_amdgcn_mfma_f32_16x16x32_bf16(Ah1, Bl[1][1], acc, 0, 0, 0);
            float k0 = fmaf(2.f, acc[0], -x2v[0]);
            float k1 = fmaf(2.f, acc[1], -x2v[1]);
            float k2 = fmaf(2.f, acc[2], -x2v[2]);
            float k3 = fmaf(2.f, acc[3], -x2v[3]);
            APPEND(k0, tau1, ln1, mbase + 0)
            APPEND(k1, tau1, ln1, mbase + 1)
            APPEND(k2, tau1, ln1, mbase + 2)
            APPEND(k3, tau1, ln1, mbase + 3)
        }
        Ah0 = nAh0; Al0 = nAl0; Ah1 = nAh1; Al1 = nAl1; x2v = nx2;
    }

    __syncthreads();
    int r = threadIdx.x >> 3, sub = threadIdx.x & 7;
    int c = cnt_s[r];
    size_t grow = (size_t)b * N_ + ng * 32 + r;
    if (sub == 0) cntg[grow] = c;
    int cc = min(c, CAP);
    for (int s = sub; s < cc; s += 8) candg[grow * CAP + s] = buf_s[r][s];
}

// wave-per-row exact fp64 re-rank of candidates -> true top-9
__global__ void k_refine(const float* __restrict__ xT, const unsigned short* __restrict__ candg,
                         const int* __restrict__ cntg, int* __restrict__ idx9) {
    int wave = threadIdx.x >> 6, lane = threadIdx.x & 63;
    int row = blockIdx.x * 4 + wave;
    int cnt = cntg[row];
    if (cnt < KNN || cnt > CAP) return;   // fallback kernel handles
    int b = row >> 12;
    float xi = xT[(size_t)row * C_ + lane];   // lane = channel, coalesced
    double mykey = -1e300; int myidx = 0x7fffffff;
    for (int j = 0; j < cnt; ++j) {
        int m = candg[(size_t)row * CAP + j];
        float xm = xT[(((size_t)b << 12) + m) * C_ + lane];
        double d  = (double)xi * (double)xm;
        double s2 = (double)xm * (double)xm;
#pragma unroll
        for (int o = 32; o; o >>= 1) { d += __shfl_xor(d, o); s2 += __shfl_xor(s2, o); }
        double key = 2.0 * d - s2;
        if (lane == j) { mykey = key; myidx = m; }
    }
    for (int r = 0; r < KNN; ++r) {
        double k = mykey; int ix = myidx;
#pragma unroll
        for (int o = 32; o; o >>= 1) {
            double ok = __shfl_xor(k, o); int oi = __shfl_xor(ix, o);
            bool take = (ok > k) || (ok == k && oi < ix);
            k = take ? ok : k; ix = take ? oi : ix;
        }
        if (lane == 0) idx9[(size_t)row * KNN + r] = ix;
        if (myidx == ix) { mykey = -1e300; myidx = 0x7fffffff; }
    }
}

// exact fp64 full scan for rows where the threshold buffer failed (rare)
__global__ void k_fallback(const float* __restrict__ xT, const int* __restrict__ cntg,
                           int* __restrict__ idx9) {
    int wave = threadIdx.x >> 6, lane = threadIdx.x & 63;
    int w = blockIdx.x * 4 + wave;
    for (int rr = 0; rr < 16; ++rr) {
        int row = w * 16 + rr;
        int cnt = cntg[row];
        if (cnt >= KNN && cnt <= CAP) continue;
        int b = row >> 12;
        const float* xi = xT + (size_t)row * C_;
        double sk[9]; int si[9];
#pragma unroll
        for (int j = 0; j < 9; ++j) { sk[j] = -1e300; si[j] = 0x7fffffff; }
        for (int mb = 0; mb < N_; mb += 64) {
            int m = mb + lane;
            const float* xm = xT + (((size_t)b << 12) + m) * C_;
            double d = 0.0, s2 = 0.0;
            for (int c = 0; c < C_; ++c) {
                double v = xm[c];
                d += (double)xi[c] * v; s2 += v * v;
            }
            double key = 2.0 * d - s2;
            if (key > sk[0] || (key == sk[0] && m < si[0])) {
                sk[0] = key; si[0] = m;
#pragma unroll
                for (int j = 0; j < 8; ++j) {
                    bool sw = (sk[j] > sk[j + 1]) || (sk[j] == sk[j + 1] && si[j] < si[j + 1]);
                    double tk = sk[j]; int ti = si[j];
                    sk[j]     = sw ? sk[j + 1] : sk[j];
                    si[j]     = sw ? si[j + 1] : si[j];
                    sk[j + 1] = sw ? tk : sk[j + 1];
                    si[j + 1] = sw ? ti : si[j + 1];
                }
            }
        }
        for (int r = 0; r < KNN; ++r) {
            double k = sk[8]; int ix = si[8];
#pragma unroll
            for (int o = 32; o; o >>= 1) {
                double ok = __shfl_xor(k, o); int oi = __shfl_xor(ix, o);
                bool take = (ok > k) || (ok == k && oi < ix);
                k = take ? ok : k; ix = take ? oi : ix;
            }
            if (lane == 0) idx9[(size_t)row * KNN + r] = ix;
            if (si[8] == ix) {
#pragma unroll
                for (int j = 8; j > 0; --j) { sk[j] = sk[j - 1]; si[j] = si[j - 1]; }
                sk[0] = -1e300; si[0] = 0x7fffffff;
            }
        }
    }
}

__global__ void k_xmax(const float* __restrict__ xT, const int* __restrict__ idx9,
                       float* __restrict__ xmaxT) {
    int wave = threadIdx.x >> 6, lane = threadIdx.x & 63;
    int row = blockIdx.x * 4 + wave;
    int b = row >> 12;
    int n = row & (N_ - 1);
    const int* id = idx9 + (size_t)row * KNN;
    float m = -FLT_MAX;
#pragma unroll
    for (int k = 0; k < KNN; ++k) {
        int j = id[k];
        m = fmaxf(m, xT[((size_t)b * N_ + j) * C_ + lane]);
    }
    float xic = xT[((size_t)b * N_ + n) * C_ + lane];
    xmaxT[(size_t)row * C_ + lane] = m - xic;
}

__global__ void k_gemm(const float* __restrict__ xT, const float* __restrict__ xmaxT,
                       const float* __restrict__ WT, const float* __restrict__ bias,
                       float* __restrict__ out) {
    __shared__ float h[64][129];
    int b  = blockIdx.x >> 6;
    int n0 = (blockIdx.x & 63) * 64;
    int tid = threadIdx.x;
    for (int i = 0; i < 16; ++i) {
        int e = i * 256 + tid;
        int nn = e >> 6, c = e & 63;
        size_t g = ((size_t)b * N_ + n0 + nn) * C_ + c;
        h[nn][c]      = xT[g];
        h[nn][64 + c] = xmaxT[g];
    }
    __syncthreads();
    int wave = tid >> 6, lane = tid & 63;
    int o0 = wave * 32;
    float acc[32];
#pragma unroll
    for (int j = 0; j < 32; ++j) acc[j] = 0.f;
    for (int c = 0; c < 2 * C_; ++c) {
        float hv = h[lane][c];
        const float4* wrow = (const float4*)(WT + (size_t)c * OUT_ + o0);
#pragma unroll
        for (int j4 = 0; j4 < 8; ++j4) {
            float4 w = wrow[j4];
            acc[j4 * 4 + 0] += w.x * hv;
            acc[j4 * 4 + 1] += w.y * hv;
            acc[j4 * 4 + 2] += w.z * hv;
            acc[j4 * 4 + 3] += w.w * hv;
        }
    }
#pragma unroll
    for (int j = 0; j < 32; ++j) {
        float v = acc[j] + bias[o0 + j];
        v = fmaxf(v, 0.f);
        out[((size_t)b * OUT_ + o0 + j) * N_ + n0 + lane] = v;
    }
}

extern "C" void kernel_launch(void* const* d_in, const int* in_sizes, int n_in,
                              void* d_out, int out_size, void* d_ws, size_t ws_size,
                              hipStream_t stream) {
    const float* x    = (const float*)d_in[0];
    const float* W    = (const float*)d_in[1];
    const float* bias = (const float*)d_in[2];
    float* out = (float*)d_out;
    char* ws = (char*)d_ws;

    float*          xT    = (float*)(ws);
    unsigned short* xfrag = (unsigned short*)(ws + 8388608);
    float*          xmaxT = (float*)(ws + 8388608);       // aliases xfrag (dead by then)
    float*          x2    = (float*)(ws + 16777216);
    float*          WT    = (float*)(ws + 16908288);
    unsigned short* cand  = (unsigned short*)(ws + 16973824);
    int*            cnt   = (int*)(ws + 21168128);
    int*            idx9  = (int*)(ws + 21299200);

    k_wt       <<<dim3(64),   dim3(256), 0, stream>>>(W, WT);
    k_transpose<<<dim3(512),  dim3(256), 0, stream>>>(x, xT, x2);
    k_prep     <<<dim3(1024), dim3(256), 0, stream>>>(xT, xfrag);
    k_topk_mf  <<<dim3(1024), dim3(256), 0, stream>>>(xfrag, x2, cand, cnt);
    k_refine   <<<dim3(8192), dim3(256), 0, stream>>>(xT, cand, cnt, idx9);
    k_fallback <<<dim3(512),  dim3(256), 0, stream>>>(xT, cnt, idx9);
    k_xmax     <<<dim3(8192), dim3(256), 0, stream>>>(xT, idx9, xmaxT);
    k_gemm     <<<dim3(512),  dim3(256), 0, stream>>>(xT, xmaxT, WT, bias, out);
}

// Round 4
// 374.957 us; speedup vs baseline: 2.1972x; 1.4907x over previous
//
#include <hip/hip_runtime.h>
#include <float.h>

#define B_   8
#define C_   64
#define N_   4096
#define OUT_ 128
#define KNN  9
#define CAP  64          // candidate buffer capacity per row (refine handles <=64)
#define TAU_A 2.3f       // threshold: tau = TAU_A*sigma_n - 64

typedef __attribute__((ext_vector_type(8))) short short8;
typedef __attribute__((ext_vector_type(4))) float f32x4;

__device__ inline unsigned short f2bf(float f) {
    unsigned u = __float_as_uint(f);
    unsigned r = (u + 0x7fffu + ((u >> 16) & 1u)) >> 16;
    return (unsigned short)r;
}
__device__ inline float bf2f(unsigned short s) {
    return __uint_as_float(((unsigned)s) << 16);
}

// ---------------------------------------------------------------------------
// ws layout (bytes):
//   xT:    [B][N][C] float     @ 0          (8388608)
//   xfrag: hi/lo bf16 chunks   @ 8388608    (8388608)  } aliased: xfrag dead
//   xmaxT: [B][N][C] float     @ 8388608    (8388608)  } before k_xmax writes
//   x2:    [B][N]    float     @ 16777216   (131072)
//   WT:    [2C][OUT] float     @ 16908288   (65536)
//   cand:  [B*N][64] ushort    @ 16973824   (4194304)
//   cnt:   [B*N]     int       @ 21168128   (131072)
//   idx9:  [B*N][9]  int       @ 21299200   (1179648)   total ~22.5 MB
// ---------------------------------------------------------------------------

__global__ void k_wt(const float* __restrict__ W, float* __restrict__ WT) {
    int e = blockIdx.x * 256 + threadIdx.x;
    int o = e >> 7, c = e & 127;
    WT[(size_t)c * OUT_ + o] = W[e];
}

__global__ void k_transpose(const float* __restrict__ x, float* __restrict__ xT,
                            float* __restrict__ x2) {
    __shared__ float t[C_][65];
    int b  = blockIdx.x >> 6;
    int n0 = (blockIdx.x & 63) * 64;
    int tid = threadIdx.x;
    for (int i = 0; i < 16; ++i) {
        int e = i * 256 + tid;
        int c = e >> 6, nn = e & 63;
        t[c][nn] = x[((size_t)b * C_ + c) * N_ + n0 + nn];
    }
    __syncthreads();
    for (int i = 0; i < 16; ++i) {
        int e = i * 256 + tid;
        int nn = e >> 6, c = e & 63;
        xT[((size_t)b * N_ + n0 + nn) * C_ + c] = t[c][nn];
    }
    if (tid < 64) {
        float s = 0.f;
        for (int c = 0; c < C_; ++c) { float v = t[c][tid]; s += v * v; }
        x2[(size_t)b * N_ + n0 + tid] = s;
    }
}

// build bf16 hi/lo fragment chunks from xT (mfma_f32_16x16x32_bf16 load order)
__global__ void k_prep(const float* __restrict__ xT, unsigned short* __restrict__ xfrag) {
    int tid = threadIdx.x;
    int t = blockIdx.x * 2 + (tid >> 7);        // global m-tile 0..2047
    int h = (tid >> 6) & 1;
    int L = tid & 63;
    int b = t >> 8, tb = t & 255;
    int m = tb * 16 + (L & 15);
    int ks = h * 32 + ((L >> 4) * 8);
    const float* src = xT + ((size_t)b * N_ + m) * C_ + ks;
    float4 v0 = *(const float4*)(src);
    float4 v1 = *(const float4*)(src + 4);
    float vs[8] = {v0.x, v0.y, v0.z, v0.w, v1.x, v1.y, v1.z, v1.w};
    short8 hi, lo;
#pragma unroll
    for (int j = 0; j < 8; ++j) {
        unsigned short hb = f2bf(vs[j]);
        float hf = bf2f(hb);
        unsigned short lb = f2bf(vs[j] - hf);
        hi[j] = (short)hb; lo[j] = (short)lb;
    }
    size_t cb = ((size_t)t * 4 + h * 2) * 512;   // ushort units (chunk=512 ushort)
    *(short8*)(xfrag + cb + L * 8)       = hi;
    *(short8*)(xfrag + cb + 512 + L * 8) = lo;
}

#define APPEND(KEY, TAU, LN, MIDX)                                      \
    if ((KEY) > (TAU)) {                                                \
        int sl = atomicAdd(&cnt_s[LN], 1);                              \
        if (sl < CAP) buf_s[LN][sl] = (unsigned short)(MIDX);           \
    }

// MFMA scan + threshold compaction. block = (b = blockIdx&7, ng = blockIdx>>3).
// 32 n's per block; wave w scans m in [w*1024,(w+1)*1024).
__global__ __launch_bounds__(256, 2) void k_topk_mf(const unsigned short* __restrict__ xfrag,
                                                    const float* __restrict__ x2,
                                                    unsigned short* __restrict__ candg,
                                                    int* __restrict__ cntg) {
    __shared__ int cnt_s[32];
    __shared__ unsigned short buf_s[32][CAP];
    int b    = blockIdx.x & 7;
    int ng   = blockIdx.x >> 3;
    int wave = threadIdx.x >> 6, lane = threadIdx.x & 63;
    if (threadIdx.x < 32) cnt_s[threadIdx.x] = 0;

    const short8* fr = (const short8*)xfrag;     // 16B units; chunk = 64 short8

    short8 Bh[2][2], Bl[2][2];
#pragma unroll
    for (int q = 0; q < 2; ++q)
#pragma unroll
        for (int h = 0; h < 2; ++h) {
            int ch = ((b * 256 + ng * 2 + q) * 4 + h * 2);
            Bh[q][h] = fr[(size_t)ch * 64 + lane];
            Bl[q][h] = fr[(size_t)(ch + 1) * 64 + lane];
        }

    int ln0 = lane & 15, ln1 = 16 + ln0;
    float x2n0 = x2[b * N_ + ng * 32 + ln0];
    float x2n1 = x2[b * N_ + ng * 32 + 16 + ln0];
    float tau0 = TAU_A * sqrtf(fmaf(4.f, x2n0, 128.f)) - 64.f;
    float tau1 = TAU_A * sqrtf(fmaf(4.f, x2n1, 128.f)) - 64.f;

    int mt0 = wave * 64;
    size_t cb = (size_t)(b * 256 + mt0) * 4;
    short8 Ah0 = fr[cb * 64 + lane],       Al0 = fr[(cb + 1) * 64 + lane];
    short8 Ah1 = fr[(cb + 2) * 64 + lane], Al1 = fr[(cb + 3) * 64 + lane];
    f32x4 x2v = *(const f32x4*)(x2 + b * N_ + mt0 * 16 + (lane >> 4) * 4);

    __syncthreads();   // cnt_s zeroed

    for (int i = 0; i < 64; ++i) {
        int inext = (i + 1 < 64) ? i + 1 : i;
        size_t cn = (size_t)(b * 256 + mt0 + inext) * 4;
        short8 nAh0 = fr[cn * 64 + lane],       nAl0 = fr[(cn + 1) * 64 + lane];
        short8 nAh1 = fr[(cn + 2) * 64 + lane], nAl1 = fr[(cn + 3) * 64 + lane];
        f32x4 nx2 = *(const f32x4*)(x2 + b * N_ + (mt0 + inext) * 16 + (lane >> 4) * 4);

        int mbase = (mt0 + i) * 16 + (lane >> 4) * 4;

        {   // n-tile 0
            f32x4 acc = {0.f, 0.f, 0.f, 0.f};
            acc = __builtin_amdgcn_mfma_f32_16x16x32_bf16(Ah0, Bh[0][0], acc, 0, 0, 0);
            acc = __builtin_amdgcn_mfma_f32_16x16x32_bf16(Ah1, Bh[0][1], acc, 0, 0, 0);
            acc = __builtin_amdgcn_mfma_f32_16x16x32_bf16(Al0, Bh[0][0], acc, 0, 0, 0);
            acc = __builtin_amdgcn_mfma_f32_16x16x32_bf16(Al1, Bh[0][1], acc, 0, 0, 0);
            acc = __builtin_amdgcn_mfma_f32_16x16x32_bf16(Ah0, Bl[0][0], acc, 0, 0, 0);
            acc = __builtin_amdgcn_mfma_f32_16x16x32_bf16(Ah1, Bl[0][1], acc, 0, 0, 0);
            float k0 = fmaf(2.f, acc[0], -x2v[0]);
            float k1 = fmaf(2.f, acc[1], -x2v[1]);
            float k2 = fmaf(2.f, acc[2], -x2v[2]);
            float k3 = fmaf(2.f, acc[3], -x2v[3]);
            APPEND(k0, tau0, ln0, mbase + 0)
            APPEND(k1, tau0, ln0, mbase + 1)
            APPEND(k2, tau0, ln0, mbase + 2)
            APPEND(k3, tau0, ln0, mbase + 3)
        }
        {   // n-tile 1
            f32x4 acc = {0.f, 0.f, 0.f, 0.f};
            acc = __builtin_amdgcn_mfma_f32_16x16x32_bf16(Ah0, Bh[1][0], acc, 0, 0, 0);
            acc = __builtin_amdgcn_mfma_f32_16x16x32_bf16(Ah1, Bh[1][1], acc, 0, 0, 0);
            acc = __builtin_amdgcn_mfma_f32_16x16x32_bf16(Al0, Bh[1][0], acc, 0, 0, 0);
            acc = __builtin_amdgcn_mfma_f32_16x16x32_bf16(Al1, Bh[1][1], acc, 0, 0, 0);
            acc = __builtin_amdgcn_mfma_f32_16x16x32_bf16(Ah0, Bl[1][0], acc, 0, 0, 0);
            acc = __builtin_amdgcn_mfma_f32_16x16x32_bf16(Ah1, Bl[1][1], acc, 0, 0, 0);
            float k0 = fmaf(2.f, acc[0], -x2v[0]);
            float k1 = fmaf(2.f, acc[1], -x2v[1]);
            float k2 = fmaf(2.f, acc[2], -x2v[2]);
            float k3 = fmaf(2.f, acc[3], -x2v[3]);
            APPEND(k0, tau1, ln1, mbase + 0)
            APPEND(k1, tau1, ln1, mbase + 1)
            APPEND(k2, tau1, ln1, mbase + 2)
            APPEND(k3, tau1, ln1, mbase + 3)
        }
        Ah0 = nAh0; Al0 = nAl0; Ah1 = nAh1; Al1 = nAl1; x2v = nx2;
    }

    __syncthreads();
    int r = threadIdx.x >> 3, sub = threadIdx.x & 7;
    int c = cnt_s[r];
    size_t grow = (size_t)b * N_ + ng * 32 + r;
    if (sub == 0) cntg[grow] = c;
    int cc = min(c, CAP);
    for (int s = sub; s < cc; s += 8) candg[grow * CAP + s] = buf_s[r][s];
}

// lane-per-candidate exact fp64 re-rank -> true top-9. Wave per row.
__global__ void k_refine(const float* __restrict__ xT, const unsigned short* __restrict__ candg,
                         const int* __restrict__ cntg, int* __restrict__ idx9) {
    int wave = threadIdx.x >> 6, lane = threadIdx.x & 63;
    int row = blockIdx.x * 4 + wave;
    int cnt = cntg[row];
    if (cnt < KNN || cnt > CAP) return;   // fallback kernel handles
    int b = row >> 12;
    int j = min(lane, cnt - 1);
    int m = candg[(size_t)row * CAP + j];
    const float* xi = xT + (size_t)row * C_;                 // broadcast loads
    const float* xm = xT + (((size_t)b << 12) + m) * C_;     // per-lane stream
    double d = 0.0, s2 = 0.0;
#pragma unroll
    for (int c4 = 0; c4 < 16; ++c4) {
        float4 a = *(const float4*)(xi + c4 * 4);
        float4 v = *(const float4*)(xm + c4 * 4);
        d  = fma((double)a.x, (double)v.x, d);  s2 = fma((double)v.x, (double)v.x, s2);
        d  = fma((double)a.y, (double)v.y, d);  s2 = fma((double)v.y, (double)v.y, s2);
        d  = fma((double)a.z, (double)v.z, d);  s2 = fma((double)v.z, (double)v.z, s2);
        d  = fma((double)a.w, (double)v.w, d);  s2 = fma((double)v.w, (double)v.w, s2);
    }
    double mykey = 2.0 * d - s2;
    int myidx = m;
    if (lane >= cnt) { mykey = -1e300; myidx = 0x7fffffff; }
    for (int r = 0; r < KNN; ++r) {
        double k = mykey; int ix = myidx;
#pragma unroll
        for (int o = 32; o; o >>= 1) {
            double ok = __shfl_xor(k, o); int oi = __shfl_xor(ix, o);
            bool take = (ok > k) || (ok == k && oi < ix);
            k = take ? ok : k; ix = take ? oi : ix;
        }
        if (lane == 0) idx9[(size_t)row * KNN + r] = ix;
        if (myidx == ix) { mykey = -1e300; myidx = 0x7fffffff; }  // indices unique per row
    }
}

// exact fp64 full scan for rows where the threshold buffer failed (rare)
__global__ void k_fallback(const float* __restrict__ xT, const int* __restrict__ cntg,
                           int* __restrict__ idx9) {
    int wave = threadIdx.x >> 6, lane = threadIdx.x & 63;
    int w = blockIdx.x * 4 + wave;
    for (int rr = 0; rr < 16; ++rr) {
        int row = w * 16 + rr;
        int cnt = cntg[row];
        if (cnt >= KNN && cnt <= CAP) continue;
        int b = row >> 12;
        const float* xi = xT + (size_t)row * C_;
        double sk[9]; int si[9];
#pragma unroll
        for (int j = 0; j < 9; ++j) { sk[j] = -1e300; si[j] = 0x7fffffff; }
        for (int mb = 0; mb < N_; mb += 64) {
            int m = mb + lane;
            const float* xm = xT + (((size_t)b << 12) + m) * C_;
            double d = 0.0, s2 = 0.0;
            for (int c = 0; c < C_; ++c) {
                double v = xm[c];
                d += (double)xi[c] * v; s2 += v * v;
            }
            double key = 2.0 * d - s2;
            if (key > sk[0] || (key == sk[0] && m < si[0])) {
                sk[0] = key; si[0] = m;
#pragma unroll
                for (int j = 0; j < 8; ++j) {
                    bool sw = (sk[j] > sk[j + 1]) || (sk[j] == sk[j + 1] && si[j] < si[j + 1]);
                    double tk = sk[j]; int ti = si[j];
                    sk[j]     = sw ? sk[j + 1] : sk[j];
                    si[j]     = sw ? si[j + 1] : si[j];
                    sk[j + 1] = sw ? tk : sk[j + 1];
                    si[j + 1] = sw ? ti : si[j + 1];
                }
            }
        }
        for (int r = 0; r < KNN; ++r) {
            double k = sk[8]; int ix = si[8];
#pragma unroll
            for (int o = 32; o; o >>= 1) {
                double ok = __shfl_xor(k, o); int oi = __shfl_xor(ix, o);
                bool take = (ok > k) || (ok == k && oi < ix);
                k = take ? ok : k; ix = take ? oi : ix;
            }
            if (lane == 0) idx9[(size_t)row * KNN + r] = ix;
            if (si[8] == ix) {
#pragma unroll
                for (int j = 8; j > 0; --j) { sk[j] = sk[j - 1]; si[j] = si[j - 1]; }
                sk[0] = -1e300; si[0] = 0x7fffffff;
            }
        }
    }
}

__global__ void k_xmax(const float* __restrict__ xT, const int* __restrict__ idx9,
                       float* __restrict__ xmaxT) {
    int wave = threadIdx.x >> 6, lane = threadIdx.x & 63;
    int row = blockIdx.x * 4 + wave;
    int b = row >> 12;
    int n = row & (N_ - 1);
    const int* id = idx9 + (size_t)row * KNN;
    float m = -FLT_MAX;
#pragma unroll
    for (int k = 0; k < KNN; ++k) {
        int j = id[k];
        m = fmaxf(m, xT[((size_t)b * N_ + j) * C_ + lane]);
    }
    float xic = xT[((size_t)b * N_ + n) * C_ + lane];
    xmaxT[(size_t)row * C_ + lane] = m - xic;
}

__global__ void k_gemm(const float* __restrict__ xT, const float* __restrict__ xmaxT,
                       const float* __restrict__ WT, const float* __restrict__ bias,
                       float* __restrict__ out) {
    __shared__ float h[64][129];
    int b  = blockIdx.x >> 6;
    int n0 = (blockIdx.x & 63) * 64;
    int tid = threadIdx.x;
    for (int i = 0; i < 16; ++i) {
        int e = i * 256 + tid;
        int nn = e >> 6, c = e & 63;
        size_t g = ((size_t)b * N_ + n0 + nn) * C_ + c;
        h[nn][c]      = xT[g];
        h[nn][64 + c] = xmaxT[g];
    }
    __syncthreads();
    int wave = tid >> 6, lane = tid & 63;
    int o0 = wave * 32;
    float acc[32];
#pragma unroll
    for (int j = 0; j < 32; ++j) acc[j] = 0.f;
    for (int c = 0; c < 2 * C_; ++c) {
        float hv = h[lane][c];
        const float4* wrow = (const float4*)(WT + (size_t)c * OUT_ + o0);
#pragma unroll
        for (int j4 = 0; j4 < 8; ++j4) {
            float4 w = wrow[j4];
            acc[j4 * 4 + 0] += w.x * hv;
            acc[j4 * 4 + 1] += w.y * hv;
            acc[j4 * 4 + 2] += w.z * hv;
            acc[j4 * 4 + 3] += w.w * hv;
        }
    }
#pragma unroll
    for (int j = 0; j < 32; ++j) {
        float v = acc[j] + bias[o0 + j];
        v = fmaxf(v, 0.f);
        out[((size_t)b * OUT_ + o0 + j) * N_ + n0 + lane] = v;
    }
}

extern "C" void kernel_launch(void* const* d_in, const int* in_sizes, int n_in,
                              void* d_out, int out_size, void* d_ws, size_t ws_size,
                              hipStream_t stream) {
    const float* x    = (const float*)d_in[0];
    const float* W    = (const float*)d_in[1];
    const float* bias = (const float*)d_in[2];
    float* out = (float*)d_out;
    char* ws = (char*)d_ws;

    float*          xT    = (float*)(ws);
    unsigned short* xfrag = (unsigned short*)(ws + 8388608);
    float*          xmaxT = (float*)(ws + 8388608);       // aliases xfrag (dead by then)
    float*          x2    = (float*)(ws + 16777216);
    float*          WT    = (float*)(ws + 16908288);
    unsigned short* cand  = (unsigned short*)(ws + 16973824);
    int*            cnt   = (int*)(ws + 21168128);
    int*            idx9  = (int*)(ws + 21299200);

    k_wt       <<<dim3(64),   dim3(256), 0, stream>>>(W, WT);
    k_transpose<<<dim3(512),  dim3(256), 0, stream>>>(x, xT, x2);
    k_prep     <<<dim3(1024), dim3(256), 0, stream>>>(xT, xfrag);
    k_topk_mf  <<<dim3(1024), dim3(256), 0, stream>>>(xfrag, x2, cand, cnt);
    k_refine   <<<dim3(8192), dim3(256), 0, stream>>>(xT, cand, cnt, idx9);
    k_fallback <<<dim3(512),  dim3(256), 0, stream>>>(xT, cnt, idx9);
    k_xmax     <<<dim3(8192), dim3(256), 0, stream>>>(xT, idx9, xmaxT);
    k_gemm     <<<dim3(512),  dim3(256), 0, stream>>>(xT, xmaxT, WT, bias, out);
}